// Round 1
// baseline (418.552 us; speedup 1.0000x reference)
//
#include <hip/hip_runtime.h>
#include <hip/hip_bf16.h>

typedef _Float16 f16x8 __attribute__((ext_vector_type(8)));
typedef float f32x4 __attribute__((ext_vector_type(4)));

__device__ __forceinline__ void gload_lds16(const void* gptr, void* lptr) {
  __builtin_amdgcn_global_load_lds(
      (const __attribute__((address_space(1))) void*)gptr,
      (__attribute__((address_space(3))) void*)lptr, 16, 0, 0);
}

// ---------------- K1a: downsample x -> f (fp16), sum_c f^2, m = avgpool(mask) ----------
__global__ void k_pre(const float* __restrict__ x, const float* __restrict__ mask,
                      _Float16* __restrict__ f_h, float* __restrict__ sumsq,
                      float* __restrict__ mlow) {
  int blk = blockIdx.x;              // b*4096 + i*64 + j
  int b = blk >> 12, ij = blk & 4095;
  int i = ij >> 6, j = ij & 63;
  int c = threadIdx.x;               // 64 threads = 1 wave
  size_t base = ((size_t)(b * 128 + 2 * i) * 128 + 2 * j) * 64 + c;
  float f = 0.25f * (x[base] + x[base + 64] + x[base + 128 * 64] + x[base + 128 * 64 + 64]);
  f_h[(size_t)blk * 64 + c] = (_Float16)f;
  float fsq = f * f;
  for (int off = 32; off; off >>= 1) fsq += __shfl_down(fsq, off);
  if (c == 0) {
    sumsq[blk] = fsq;
    size_t mb = (size_t)(b * 128 + 2 * i) * 128 + 2 * j;
    mlow[blk] = 0.25f * (mask[mb] + mask[mb + 1] + mask[mb + 128] + mask[mb + 129]);
  }
}

// ---------------- K1b: invn[l], mm[l] ----------------
__global__ void k_norm_mm(const float* __restrict__ sumsq, const float* __restrict__ mlow,
                          float* __restrict__ invn, float* __restrict__ mmb) {
  int t = blockIdx.x * 256 + threadIdx.x;  // 8192
  int b = t >> 12, l = t & 4095;
  int li = l >> 6, lj = l & 63;
  float s = 0.f;
  bool ok = true;
  for (int dh = -1; dh <= 1; ++dh)
    for (int dw = -1; dw <= 1; ++dw) {
      int ii = li + dh, jj = lj + dw;
      float mv = 0.f;
      if ((unsigned)ii < 64u && (unsigned)jj < 64u) {
        int idx = (b << 12) + ii * 64 + jj;
        s += sumsq[idx];
        mv = mlow[idx];
      }
      ok = ok && (mv == 1.0f);   // exact-1.0 patch <=> all 9 entries exactly 1.0
    }
  invn[t] = 1.0f / fmaxf(sqrtf(s), 1e-4f);
  mmb[t] = ok ? 1.0f : 0.0f;
}

// ---------------- K1p: P[b][l][kk*64+c] = f patches (SAME, stride1) ----------------
__global__ void k_build_p(const _Float16* __restrict__ f_h, _Float16* __restrict__ P) {
  int blk = blockIdx.x;  // b*4096+l
  int b = blk >> 12, l = blk & 4095;
  int li = l >> 6, lj = l & 63, c = threadIdx.x;
  _Float16* dst = P + (size_t)blk * 576 + c;
#pragma unroll
  for (int kk = 0; kk < 9; ++kk) {
    int kh = kk / 3, kw = kk % 3;
    int ii = li + kh - 1, jj = lj + kw - 1;
    _Float16 v = (_Float16)0.f;
    if ((unsigned)ii < 64u && (unsigned)jj < 64u)
      v = f_h[((size_t)(b << 12) + ii * 64 + jj) * 64 + c];
    dst[kk * 64] = v;
  }
}

// ---------------- K1c: Rt[b][n][l] = raw x patches (stride2), pre-transposed ----------
__global__ void k_build_rt(const float* __restrict__ x, _Float16* __restrict__ Rt) {
  int kh = blockIdx.x, li = blockIdx.y, b = blockIdx.z;
  int r = 2 * li + kh;
  if (r >= 128) return;  // those Rt entries stay zero (memset)
  __shared__ float xrow[128 * 65];
  for (int t = threadIdx.x; t < 8192; t += 256) {
    int v = t >> 6, c = t & 63;
    xrow[v * 65 + c] = x[((size_t)(b * 128 + r) * 128 + v) * 64 + c];
  }
  __syncthreads();
  for (int idx = threadIdx.x; idx < 12288; idx += 256) {
    int lj = idx & 63, rest = idx >> 6;
    int c = rest & 63, kw = rest >> 6;
    int v = 2 * lj + kw;
    float val = (v < 128) ? xrow[v * 65 + c] : 0.f;
    int n = (kh * 3 + kw) * 64 + c;
    Rt[((size_t)b * 640 + n) * 4096 + li * 64 + lj] = (_Float16)val;
  }
}

// ---------------- K2: att[b][p][l] = invn[l] * sum_k P[p,k] P[l,k]  (M=N=4096,K=576) ---
__global__ __launch_bounds__(256) void k_gemm_sim(const _Float16* __restrict__ P,
                                                  const float* __restrict__ invn,
                                                  float* __restrict__ att) {
  int b = blockIdx.z;
  const _Float16* Ab = P + (size_t)b * 4096 * 576;
  int rowBase = blockIdx.y * 128, colBase = blockIdx.x * 128;
  __shared__ alignas(16) _Float16 As[128 * 32];
  __shared__ alignas(16) _Float16 Bs[128 * 32];
  int tid = threadIdx.x, wave = tid >> 6, lane = tid & 63;
  int q = lane >> 4, rr = lane & 15;
  int wr = (wave >> 1) * 64, wc = (wave & 1) * 64;
  f32x4 acc[4][4] = {};
  for (int kt = 0; kt < 576; kt += 32) {
    __syncthreads();
#pragma unroll
    for (int t = 0; t < 2; ++t) {
      int chunk = t * 256 + wave * 64 + lane;  // 512 chunks of 16B per tile
      int row = chunk >> 2, kc = (chunk & 3) * 8;
      gload_lds16(Ab + (size_t)(rowBase + row) * 576 + kt + kc,
                  As + (size_t)(t * 256 + wave * 64) * 8);
      gload_lds16(Ab + (size_t)(colBase + row) * 576 + kt + kc,
                  Bs + (size_t)(t * 256 + wave * 64) * 8);
    }
    __syncthreads();
    f16x8 af[4], bf[4];
#pragma unroll
    for (int mi = 0; mi < 4; ++mi)
      af[mi] = *(const f16x8*)(As + (wr + mi * 16 + rr) * 32 + q * 8);
#pragma unroll
    for (int ni = 0; ni < 4; ++ni)
      bf[ni] = *(const f16x8*)(Bs + (wc + ni * 16 + rr) * 32 + q * 8);
#pragma unroll
    for (int mi = 0; mi < 4; ++mi)
#pragma unroll
      for (int ni = 0; ni < 4; ++ni)
        acc[mi][ni] = __builtin_amdgcn_mfma_f32_16x16x32_f16(af[mi], bf[ni], acc[mi][ni], 0, 0, 0);
  }
  float* attb = att + ((size_t)b << 24);
#pragma unroll
  for (int ni = 0; ni < 4; ++ni) {
    int gc = colBase + wc + ni * 16 + rr;
    float sc = invn[(b << 12) + gc];
#pragma unroll
    for (int mi = 0; mi < 4; ++mi)
#pragma unroll
      for (int reg = 0; reg < 4; ++reg) {
        int gr = rowBase + wr + mi * 16 + q * 4 + reg;
        attb[((size_t)gr << 12) + gc] = acc[mi][ni][reg] * sc;
      }
  }
}

// ---------------- K3: fuse (two diagonal convs) + masked softmax -> A (fp16) ----------
__global__ __launch_bounds__(256) void k_fuse_softmax(const float* __restrict__ att,
                                                      const float* __restrict__ mmb,
                                                      _Float16* __restrict__ Aw) {
  int blk = blockIdx.x;          // b*4096 + p
  int b = blk >> 12, p = blk & 4095;
  const float* Y = att + ((size_t)b << 24);
  int tid = threadIdx.x;
  int pi = p >> 6, pj = p & 63;
  int acol = pj * 64 + pi;       // col-major flat index of p
  float z[16];
  float mx = -1e30f;
#pragma unroll
  for (int s = 0; s < 16; ++s) {
    int l = s * 256 + tid;
    float mml = mmb[(b << 12) + l];
    float zz = 0.f;
    if (mml == 1.0f) {
      int li = l >> 6, lj = l & 63;
      int bcol = lj * 64 + li;
      float F = 0.f;
#pragma unroll
      for (int d2 = -1; d2 <= 1; ++d2) {
        int a2 = acol + d2, b2 = bcol + d2;
        if ((unsigned)a2 < 4096u && (unsigned)b2 < 4096u) {
          int p2 = (a2 & 63) * 64 + (a2 >> 6);
          int l2 = (b2 & 63) * 64 + (b2 >> 6);
#pragma unroll
          for (int d1 = -1; d1 <= 1; ++d1) {
            int qq = p2 + d1, rr2 = l2 + d1;
            if ((unsigned)qq < 4096u && (unsigned)rr2 < 4096u)
              F += Y[((size_t)qq << 12) + rr2];
          }
        }
      }
      zz = F * 10.f;
    }
    z[s] = zz;
    mx = fmaxf(mx, zz);
  }
  __shared__ float red[4];
  for (int off = 32; off; off >>= 1) mx = fmaxf(mx, __shfl_down(mx, off));
  if ((tid & 63) == 0) red[tid >> 6] = mx;
  __syncthreads();
  mx = fmaxf(fmaxf(red[0], red[1]), fmaxf(red[2], red[3]));
  float esum = 0.f;
#pragma unroll
  for (int s = 0; s < 16; ++s) {
    z[s] = __expf(z[s] - mx);   // masked: exp(0 - mx), included in denom (matches ref)
    esum += z[s];
  }
  for (int off = 32; off; off >>= 1) esum += __shfl_down(esum, off);
  __syncthreads();
  if ((tid & 63) == 0) red[tid >> 6] = esum;
  __syncthreads();
  float inv = 1.f / (red[0] + red[1] + red[2] + red[3]);
  _Float16* Ap = Aw + ((size_t)blk << 12);
#pragma unroll
  for (int s = 0; s < 16; ++s) {
    int l = s * 256 + tid;
    Ap[l] = (_Float16)(z[s] * inv * mmb[(b << 12) + l]);
  }
}

// ---------------- K4: G = A * Rt^T, atomic scatter into y (adjoint of strided conv) ----
__global__ __launch_bounds__(256) void k_gemm_recon(const _Float16* __restrict__ Aw,
                                                    const _Float16* __restrict__ Rt,
                                                    float* __restrict__ y) {
  int b = blockIdx.z;
  const _Float16* Ab = Aw + ((size_t)b << 24);
  const _Float16* Bb = Rt + (size_t)b * 640 * 4096;
  int rowBase = blockIdx.y * 128, colBase = blockIdx.x * 128;  // col over 640 (576 + pad)
  __shared__ alignas(16) _Float16 As[128 * 32];
  __shared__ alignas(16) _Float16 Bs[128 * 32];
  int tid = threadIdx.x, wave = tid >> 6, lane = tid & 63;
  int q = lane >> 4, rr = lane & 15;
  int wr = (wave >> 1) * 64, wc = (wave & 1) * 64;
  f32x4 acc[4][4] = {};
  for (int kt = 0; kt < 4096; kt += 32) {
    __syncthreads();
#pragma unroll
    for (int t = 0; t < 2; ++t) {
      int chunk = t * 256 + wave * 64 + lane;
      int row = chunk >> 2, kc = (chunk & 3) * 8;
      gload_lds16(Ab + ((size_t)(rowBase + row) << 12) + kt + kc,
                  As + (size_t)(t * 256 + wave * 64) * 8);
      gload_lds16(Bb + ((size_t)(colBase + row) << 12) + kt + kc,
                  Bs + (size_t)(t * 256 + wave * 64) * 8);
    }
    __syncthreads();
    f16x8 af[4], bf[4];
#pragma unroll
    for (int mi = 0; mi < 4; ++mi)
      af[mi] = *(const f16x8*)(As + (wr + mi * 16 + rr) * 32 + q * 8);
#pragma unroll
    for (int ni = 0; ni < 4; ++ni)
      bf[ni] = *(const f16x8*)(Bs + (wc + ni * 16 + rr) * 32 + q * 8);
#pragma unroll
    for (int mi = 0; mi < 4; ++mi)
#pragma unroll
      for (int ni = 0; ni < 4; ++ni)
        acc[mi][ni] = __builtin_amdgcn_mfma_f32_16x16x32_f16(af[mi], bf[ni], acc[mi][ni], 0, 0, 0);
  }
#pragma unroll
  for (int ni = 0; ni < 4; ++ni) {
    int gc = colBase + wc + ni * 16 + rr;
    if (gc < 576) {
      int kk = gc >> 6, c = gc & 63;
      int kh = kk / 3, kw = kk - kh * 3;
#pragma unroll
      for (int mi = 0; mi < 4; ++mi)
#pragma unroll
        for (int reg = 0; reg < 4; ++reg) {
          int gp = rowBase + wr + mi * 16 + q * 4 + reg;
          int i = gp >> 6, j = gp & 63;
          int u = 2 * i + kh, v = 2 * j + kw;
          if (u < 128 && v < 128)
            atomicAdd(y + (((size_t)((b * 128 + u) * 128 + v)) << 6) + c,
                      0.25f * acc[mi][ni][reg]);
        }
    }
  }
}

extern "C" void kernel_launch(void* const* d_in, const int* in_sizes, int n_in,
                              void* d_out, int out_size, void* d_ws, size_t ws_size,
                              hipStream_t stream) {
  const float* x = (const float*)d_in[0];
  const float* mask = (const float*)d_in[1];
  float* out = (float*)d_out;
  float* y = out;                 // [2][128][128][64]
  float* att = out + 2097152;     // [2][4096][4096]

  char* ws = (char*)d_ws;
  _Float16* f_h = (_Float16*)(ws + 0);            //  1,048,576 B
  float* sumsq = (float*)(ws + 0x100000);         //     32,768
  float* mlow = (float*)(ws + 0x108000);          //     32,768
  float* invn = (float*)(ws + 0x110000);          //     32,768
  float* mmb = (float*)(ws + 0x118000);           //     32,768
  _Float16* P = (_Float16*)(ws + 0x120000);       //  9,437,184
  _Float16* Rt = (_Float16*)(ws + 0xA20000);      // 10,485,760  [2][640][4096]
  _Float16* Aw = (_Float16*)(ws + 0x1420000);     // 67,108,864  [2][4096][4096]
  (void)in_sizes; (void)n_in; (void)out_size; (void)ws_size;

  hipMemsetAsync(y, 0, (size_t)2097152 * 4, stream);               // y accumulated via atomics
  hipMemsetAsync(Rt, 0, (size_t)2 * 640 * 4096 * 2, stream);       // pad rows / pad cols zero

  k_pre<<<8192, 64, 0, stream>>>(x, mask, f_h, sumsq, mlow);
  k_norm_mm<<<32, 256, 0, stream>>>(sumsq, mlow, invn, mmb);
  k_build_p<<<8192, 64, 0, stream>>>(f_h, P);
  k_build_rt<<<dim3(3, 64, 2), 256, 0, stream>>>(x, Rt);
  k_gemm_sim<<<dim3(32, 32, 2), 256, 0, stream>>>(P, invn, att);
  k_fuse_softmax<<<8192, 256, 0, stream>>>(att, mmb, Aw);
  k_gemm_recon<<<dim3(5, 32, 2), 256, 0, stream>>>(Aw, Rt, y);
}

// Round 2
// 324.595 us; speedup vs baseline: 1.2895x; 1.2895x over previous
//
#include <hip/hip_runtime.h>
#include <hip/hip_bf16.h>

typedef _Float16 f16x8 __attribute__((ext_vector_type(8)));
typedef float f32x4 __attribute__((ext_vector_type(4)));

__device__ __forceinline__ void gload_lds16(const void* gptr, void* lptr) {
  __builtin_amdgcn_global_load_lds(
      (const __attribute__((address_space(1))) void*)gptr,
      (__attribute__((address_space(3))) void*)lptr, 16, 0, 0);
}

// ---------------- K1a: downsample x -> f (fp16), sum_c f^2, m = avgpool(mask) ----------
__global__ void k_pre(const float* __restrict__ x, const float* __restrict__ mask,
                      _Float16* __restrict__ f_h, float* __restrict__ sumsq,
                      float* __restrict__ mlow) {
  int blk = blockIdx.x;              // b*4096 + i*64 + j
  int b = blk >> 12, ij = blk & 4095;
  int i = ij >> 6, j = ij & 63;
  int c = threadIdx.x;               // 64 threads = 1 wave
  size_t base = ((size_t)(b * 128 + 2 * i) * 128 + 2 * j) * 64 + c;
  float f = 0.25f * (x[base] + x[base + 64] + x[base + 128 * 64] + x[base + 128 * 64 + 64]);
  f_h[(size_t)blk * 64 + c] = (_Float16)f;
  float fsq = f * f;
  for (int off = 32; off; off >>= 1) fsq += __shfl_down(fsq, off);
  if (c == 0) {
    sumsq[blk] = fsq;
    size_t mb = (size_t)(b * 128 + 2 * i) * 128 + 2 * j;
    mlow[blk] = 0.25f * (mask[mb] + mask[mb + 1] + mask[mb + 128] + mask[mb + 129]);
  }
}

// ---------------- K1b: invn[l], mm[l] ----------------
__global__ void k_norm_mm(const float* __restrict__ sumsq, const float* __restrict__ mlow,
                          float* __restrict__ invn, float* __restrict__ mmb) {
  int t = blockIdx.x * 256 + threadIdx.x;  // 8192
  int b = t >> 12, l = t & 4095;
  int li = l >> 6, lj = l & 63;
  float s = 0.f;
  bool ok = true;
  for (int dh = -1; dh <= 1; ++dh)
    for (int dw = -1; dw <= 1; ++dw) {
      int ii = li + dh, jj = lj + dw;
      float mv = 0.f;
      if ((unsigned)ii < 64u && (unsigned)jj < 64u) {
        int idx = (b << 12) + ii * 64 + jj;
        s += sumsq[idx];
        mv = mlow[idx];
      }
      ok = ok && (mv == 1.0f);   // exact-1.0 patch <=> all 9 entries exactly 1.0
    }
  invn[t] = 1.0f / fmaxf(sqrtf(s), 1e-4f);
  mmb[t] = ok ? 1.0f : 0.0f;
}

// ---------------- K1d: deterministic compaction of active columns ----------------
__global__ void k_compact(const float* __restrict__ mmb, int* __restrict__ actIdx,
                          int* __restrict__ nAct) {
  int b = blockIdx.x;
  int t = threadIdx.x;  // 256
  __shared__ int sbuf[256];
  __shared__ int sbase;
  if (t == 0) sbase = 0;
  __syncthreads();
  for (int chunk = 0; chunk < 16; ++chunk) {
    int l = chunk * 256 + t;
    int flag = (mmb[(b << 12) + l] == 1.0f) ? 1 : 0;
    sbuf[t] = flag;
    __syncthreads();
    for (int off = 1; off < 256; off <<= 1) {
      int v = (t >= off) ? sbuf[t - off] : 0;
      __syncthreads();
      sbuf[t] += v;
      __syncthreads();
    }
    int incl = sbuf[t];
    int excl = incl - flag;
    int base = sbase;
    if (flag) {
      int pos = base + excl;
      if (pos < 1024) actIdx[(b << 10) + pos] = l;
    }
    __syncthreads();
    if (t == 255) sbase = base + incl;
    __syncthreads();
  }
  int total = sbase;
  for (int slot = t; slot < 1024; slot += 256)
    if (slot >= total) actIdx[(b << 10) + slot] = 0;  // safe index; weight will be 0
  if (t == 0) nAct[b] = (total > 1024) ? 1024 : total;
}

// ---------------- K1p: P[b][l][kk*64+c] = f patches (SAME, stride1) ----------------
__global__ void k_build_p(const _Float16* __restrict__ f_h, _Float16* __restrict__ P) {
  int blk = blockIdx.x;  // b*4096+l
  int b = blk >> 12, l = blk & 4095;
  int li = l >> 6, lj = l & 63, c = threadIdx.x;
  _Float16* dst = P + (size_t)blk * 576 + c;
#pragma unroll
  for (int kk = 0; kk < 9; ++kk) {
    int kh = kk / 3, kw = kk % 3;
    int ii = li + kh - 1, jj = lj + kw - 1;
    _Float16 v = (_Float16)0.f;
    if ((unsigned)ii < 64u && (unsigned)jj < 64u)
      v = f_h[((size_t)(b << 12) + ii * 64 + jj) * 64 + c];
    dst[kk * 64] = v;
  }
}

// ---------------- K1c: Rt[b][n][l] = raw x patches (stride2), pre-transposed ----------
__global__ void k_build_rt(const float* __restrict__ x, _Float16* __restrict__ Rt) {
  int kh = blockIdx.x, li = blockIdx.y, b = blockIdx.z;
  int r = 2 * li + kh;
  if (r >= 128) return;  // those Rt entries stay zero (memset)
  __shared__ float xrow[128 * 65];
  for (int t = threadIdx.x; t < 8192; t += 256) {
    int v = t >> 6, c = t & 63;
    xrow[v * 65 + c] = x[((size_t)(b * 128 + r) * 128 + v) * 64 + c];
  }
  __syncthreads();
  for (int idx = threadIdx.x; idx < 12288; idx += 256) {
    int lj = idx & 63, rest = idx >> 6;
    int c = rest & 63, kw = rest >> 6;
    int v = 2 * lj + kw;
    float val = (v < 128) ? xrow[v * 65 + c] : 0.f;
    int n = (kh * 3 + kw) * 64 + c;
    Rt[((size_t)b * 640 + n) * 4096 + li * 64 + lj] = (_Float16)val;
  }
}

// ---------------- K1e: Rts[b][n][s] = Rt[b][n][actIdx[s]] (compacted columns) ---------
__global__ void k_rtsub(const _Float16* __restrict__ Rt, const int* __restrict__ actIdx,
                        _Float16* __restrict__ Rts) {
  int n = blockIdx.x, b = blockIdx.y;
  const _Float16* src = Rt + ((size_t)b * 640 + n) * 4096;
  _Float16* dst = Rts + ((size_t)b * 640 + n) * 1024;
  const int* aIdx = actIdx + (b << 10);
  for (int s = threadIdx.x; s < 1024; s += 256) dst[s] = src[aIdx[s]];
}

// ---------------- K2: att[b][p][l] = invn[l] * sum_k P[p,k] P[l,k]  (M=N=4096,K=576) ---
__global__ __launch_bounds__(256) void k_gemm_sim(const _Float16* __restrict__ P,
                                                  const float* __restrict__ invn,
                                                  float* __restrict__ att) {
  int b = blockIdx.z;
  const _Float16* Ab = P + (size_t)b * 4096 * 576;
  int rowBase = blockIdx.y * 128, colBase = blockIdx.x * 128;
  __shared__ alignas(16) _Float16 As[128 * 32];
  __shared__ alignas(16) _Float16 Bs[128 * 32];
  int tid = threadIdx.x, wave = tid >> 6, lane = tid & 63;
  int q = lane >> 4, rr = lane & 15;
  int wr = (wave >> 1) * 64, wc = (wave & 1) * 64;
  f32x4 acc[4][4] = {};
  for (int kt = 0; kt < 576; kt += 32) {
    __syncthreads();
#pragma unroll
    for (int t = 0; t < 2; ++t) {
      int chunk = t * 256 + wave * 64 + lane;  // 512 chunks of 16B per tile
      int row = chunk >> 2, kc = (chunk & 3) * 8;
      gload_lds16(Ab + (size_t)(rowBase + row) * 576 + kt + kc,
                  As + (size_t)(t * 256 + wave * 64) * 8);
      gload_lds16(Ab + (size_t)(colBase + row) * 576 + kt + kc,
                  Bs + (size_t)(t * 256 + wave * 64) * 8);
    }
    __syncthreads();
    f16x8 af[4], bf[4];
#pragma unroll
    for (int mi = 0; mi < 4; ++mi)
      af[mi] = *(const f16x8*)(As + (wr + mi * 16 + rr) * 32 + q * 8);
#pragma unroll
    for (int ni = 0; ni < 4; ++ni)
      bf[ni] = *(const f16x8*)(Bs + (wc + ni * 16 + rr) * 32 + q * 8);
#pragma unroll
    for (int mi = 0; mi < 4; ++mi)
#pragma unroll
      for (int ni = 0; ni < 4; ++ni)
        acc[mi][ni] = __builtin_amdgcn_mfma_f32_16x16x32_f16(af[mi], bf[ni], acc[mi][ni], 0, 0, 0);
  }
  float* attb = att + ((size_t)b << 24);
#pragma unroll
  for (int ni = 0; ni < 4; ++ni) {
    int gc = colBase + wc + ni * 16 + rr;
    float sc = invn[(b << 12) + gc];
#pragma unroll
    for (int mi = 0; mi < 4; ++mi)
#pragma unroll
      for (int reg = 0; reg < 4; ++reg) {
        int gr = rowBase + wr + mi * 16 + q * 4 + reg;
        attb[((size_t)gr << 12) + gc] = acc[mi][ni][reg] * sc;
      }
  }
}

// ---------------- K3: fuse (9-pt diagonal stencil) + masked softmax, active cols only --
__global__ __launch_bounds__(256) void k_fuse_softmax2(const float* __restrict__ att,
                                                       const int* __restrict__ actIdx,
                                                       const int* __restrict__ nAct,
                                                       _Float16* __restrict__ Asub) {
  int blk = blockIdx.x;          // b*4096 + p
  int b = blk >> 12, p = blk & 4095;
  const float* Y = att + ((size_t)b << 24);
  const int* aIdx = actIdx + (b << 10);
  int na = nAct[b];
  int tid = threadIdx.x;
  int pi = p >> 6, pj = p & 63;
  int acol = pj * 64 + pi;       // col-major flat index of p
  float z[4];
  float mx = (na < 4096) ? 0.f : -1e30f;  // masked columns contribute logit 0
#pragma unroll
  for (int s4 = 0; s4 < 4; ++s4) {
    int slot = s4 * 256 + tid;
    float zz = -1e30f;
    if (slot < na) {
      int l = aIdx[slot];
      int li = l >> 6, lj = l & 63;
      int bcol = lj * 64 + li;
      float F = 0.f;
#pragma unroll
      for (int d2 = -1; d2 <= 1; ++d2) {
        int a2 = acol + d2, b2 = bcol + d2;
        if ((unsigned)a2 < 4096u && (unsigned)b2 < 4096u) {
          int p2 = (a2 & 63) * 64 + (a2 >> 6);
          int l2 = (b2 & 63) * 64 + (b2 >> 6);
#pragma unroll
          for (int d1 = -1; d1 <= 1; ++d1) {
            int qq = p2 + d1, rr2 = l2 + d1;
            if ((unsigned)qq < 4096u && (unsigned)rr2 < 4096u)
              F += Y[((size_t)qq << 12) + rr2];
          }
        }
      }
      zz = F * 10.f;
    }
    z[s4] = zz;
    mx = fmaxf(mx, zz);
  }
  __shared__ float red[4];
  for (int off = 32; off; off >>= 1) mx = fmaxf(mx, __shfl_down(mx, off));
  if ((tid & 63) == 0) red[tid >> 6] = mx;
  __syncthreads();
  mx = fmaxf(fmaxf(red[0], red[1]), fmaxf(red[2], red[3]));
  float e[4];
  float esum = 0.f;
#pragma unroll
  for (int s4 = 0; s4 < 4; ++s4) {
    int slot = s4 * 256 + tid;
    e[s4] = (slot < na) ? __expf(z[s4] - mx) : 0.f;
    esum += e[s4];
  }
  for (int off = 32; off; off >>= 1) esum += __shfl_down(esum, off);
  __syncthreads();
  if ((tid & 63) == 0) red[tid >> 6] = esum;
  __syncthreads();
  float total = red[0] + red[1] + red[2] + red[3] + (float)(4096 - na) * __expf(0.f - mx);
  float inv = 1.f / total;
  _Float16* Ap = Asub + ((size_t)blk << 10);
#pragma unroll
  for (int s4 = 0; s4 < 4; ++s4) Ap[s4 * 256 + tid] = (_Float16)(e[s4] * inv);
}

// ---------------- K4: G = Asub * Rts^T (K=1024), atomic scatter into y ----------------
__global__ __launch_bounds__(256) void k_gemm_recon(const _Float16* __restrict__ Asub,
                                                    const _Float16* __restrict__ Rts,
                                                    float* __restrict__ y) {
  int b = blockIdx.z;
  const _Float16* Ab = Asub + ((size_t)b << 22);
  const _Float16* Bb = Rts + (size_t)b * 640 * 1024;
  int rowBase = blockIdx.y * 128, colBase = blockIdx.x * 128;  // col over 640
  __shared__ alignas(16) _Float16 As[128 * 32];
  __shared__ alignas(16) _Float16 Bs[128 * 32];
  int tid = threadIdx.x, wave = tid >> 6, lane = tid & 63;
  int q = lane >> 4, rr = lane & 15;
  int wr = (wave >> 1) * 64, wc = (wave & 1) * 64;
  f32x4 acc[4][4] = {};
  for (int kt = 0; kt < 1024; kt += 32) {
    __syncthreads();
#pragma unroll
    for (int t = 0; t < 2; ++t) {
      int chunk = t * 256 + wave * 64 + lane;
      int row = chunk >> 2, kc = (chunk & 3) * 8;
      gload_lds16(Ab + ((size_t)(rowBase + row) << 10) + kt + kc,
                  As + (size_t)(t * 256 + wave * 64) * 8);
      gload_lds16(Bb + ((size_t)(colBase + row) << 10) + kt + kc,
                  Bs + (size_t)(t * 256 + wave * 64) * 8);
    }
    __syncthreads();
    f16x8 af[4], bf[4];
#pragma unroll
    for (int mi = 0; mi < 4; ++mi)
      af[mi] = *(const f16x8*)(As + (wr + mi * 16 + rr) * 32 + q * 8);
#pragma unroll
    for (int ni = 0; ni < 4; ++ni)
      bf[ni] = *(const f16x8*)(Bs + (wc + ni * 16 + rr) * 32 + q * 8);
#pragma unroll
    for (int mi = 0; mi < 4; ++mi)
#pragma unroll
      for (int ni = 0; ni < 4; ++ni)
        acc[mi][ni] = __builtin_amdgcn_mfma_f32_16x16x32_f16(af[mi], bf[ni], acc[mi][ni], 0, 0, 0);
  }
#pragma unroll
  for (int ni = 0; ni < 4; ++ni) {
    int gc = colBase + wc + ni * 16 + rr;
    if (gc < 576) {
      int kk = gc >> 6, c = gc & 63;
      int kh = kk / 3, kw = kk - kh * 3;
#pragma unroll
      for (int mi = 0; mi < 4; ++mi)
#pragma unroll
        for (int reg = 0; reg < 4; ++reg) {
          int gp = rowBase + wr + mi * 16 + q * 4 + reg;
          int i = gp >> 6, j = gp & 63;
          int u = 2 * i + kh, v = 2 * j + kw;
          if (u < 128 && v < 128)
            atomicAdd(y + (((size_t)((b * 128 + u) * 128 + v)) << 6) + c,
                      0.25f * acc[mi][ni][reg]);
        }
    }
  }
}

extern "C" void kernel_launch(void* const* d_in, const int* in_sizes, int n_in,
                              void* d_out, int out_size, void* d_ws, size_t ws_size,
                              hipStream_t stream) {
  const float* x = (const float*)d_in[0];
  const float* mask = (const float*)d_in[1];
  float* out = (float*)d_out;
  float* y = out;                 // [2][128][128][64]
  float* att = out + 2097152;     // [2][4096][4096]

  char* ws = (char*)d_ws;
  _Float16* f_h = (_Float16*)(ws + 0);            //  1,048,576 B
  float* sumsq = (float*)(ws + 0x100000);         //     32,768
  float* mlow = (float*)(ws + 0x108000);          //     32,768
  float* invn = (float*)(ws + 0x110000);          //     32,768
  float* mmb = (float*)(ws + 0x118000);           //     32,768
  _Float16* P = (_Float16*)(ws + 0x120000);       //  9,437,184
  _Float16* Rt = (_Float16*)(ws + 0xA20000);      // 10,485,760  [2][640][4096]
  int* actIdx = (int*)(ws + 0x1420000);           //      8,192  [2][1024]
  int* nAct = (int*)(ws + 0x1422000);             //          8
  _Float16* Rts = (_Float16*)(ws + 0x1430000);    //  2,621,440  [2][640][1024]
  _Float16* Asub = (_Float16*)(ws + 0x16B0000);   // 16,777,216  [2][4096][1024]
  (void)in_sizes; (void)n_in; (void)out_size; (void)ws_size;

  hipMemsetAsync(y, 0, (size_t)2097152 * 4, stream);               // y accumulated via atomics
  hipMemsetAsync(Rt, 0, (size_t)2 * 640 * 4096 * 2, stream);       // pad rows / pad cols zero

  k_pre<<<8192, 64, 0, stream>>>(x, mask, f_h, sumsq, mlow);
  k_norm_mm<<<32, 256, 0, stream>>>(sumsq, mlow, invn, mmb);
  k_compact<<<2, 256, 0, stream>>>(mmb, actIdx, nAct);
  k_build_p<<<8192, 64, 0, stream>>>(f_h, P);
  k_build_rt<<<dim3(3, 64, 2), 256, 0, stream>>>(x, Rt);
  k_rtsub<<<dim3(640, 2), 256, 0, stream>>>(Rt, actIdx, Rts);
  k_gemm_sim<<<dim3(32, 32, 2), 256, 0, stream>>>(P, invn, att);
  k_fuse_softmax2<<<8192, 256, 0, stream>>>(att, actIdx, nAct, Asub);
  k_gemm_recon<<<dim3(5, 32, 2), 256, 0, stream>>>(Asub, Rts, y);
}

// Round 3
// 321.264 us; speedup vs baseline: 1.3028x; 1.0104x over previous
//
#include <hip/hip_runtime.h>
#include <hip/hip_bf16.h>

typedef _Float16 f16x8 __attribute__((ext_vector_type(8)));
typedef float f32x4 __attribute__((ext_vector_type(4)));

__device__ __forceinline__ void gload_lds16(const void* gptr, void* lptr) {
  __builtin_amdgcn_global_load_lds(
      (const __attribute__((address_space(1))) void*)gptr,
      (__attribute__((address_space(3))) void*)lptr, 16, 0, 0);
}

// ---------------- K1a: downsample x -> f (fp16), sum_c f^2, m = avgpool(mask) ----------
__global__ void k_pre(const float* __restrict__ x, const float* __restrict__ mask,
                      _Float16* __restrict__ f_h, float* __restrict__ sumsq,
                      float* __restrict__ mlow) {
  int blk = blockIdx.x;              // b*4096 + i*64 + j
  int b = blk >> 12, ij = blk & 4095;
  int i = ij >> 6, j = ij & 63;
  int c = threadIdx.x;               // 64 threads = 1 wave
  size_t base = ((size_t)(b * 128 + 2 * i) * 128 + 2 * j) * 64 + c;
  float f = 0.25f * (x[base] + x[base + 64] + x[base + 128 * 64] + x[base + 128 * 64 + 64]);
  f_h[(size_t)blk * 64 + c] = (_Float16)f;
  float fsq = f * f;
  for (int off = 32; off; off >>= 1) fsq += __shfl_down(fsq, off);
  if (c == 0) {
    sumsq[blk] = fsq;
    size_t mb = (size_t)(b * 128 + 2 * i) * 128 + 2 * j;
    mlow[blk] = 0.25f * (mask[mb] + mask[mb + 1] + mask[mb + 128] + mask[mb + 129]);
  }
}

// ---------------- K1b: invn[l], mm[l] ----------------
__global__ void k_norm_mm(const float* __restrict__ sumsq, const float* __restrict__ mlow,
                          float* __restrict__ invn, float* __restrict__ mmb) {
  int t = blockIdx.x * 256 + threadIdx.x;  // 8192
  int b = t >> 12, l = t & 4095;
  int li = l >> 6, lj = l & 63;
  float s = 0.f;
  bool ok = true;
  for (int dh = -1; dh <= 1; ++dh)
    for (int dw = -1; dw <= 1; ++dw) {
      int ii = li + dh, jj = lj + dw;
      float mv = 0.f;
      if ((unsigned)ii < 64u && (unsigned)jj < 64u) {
        int idx = (b << 12) + ii * 64 + jj;
        s += sumsq[idx];
        mv = mlow[idx];
      }
      ok = ok && (mv == 1.0f);   // exact-1.0 patch <=> all 9 entries exactly 1.0
    }
  invn[t] = 1.0f / fmaxf(sqrtf(s), 1e-4f);
  mmb[t] = ok ? 1.0f : 0.0f;
}

// ---------------- K1d: deterministic compaction of active columns (ballot scan) -------
__global__ void k_compact(const float* __restrict__ mmb, int* __restrict__ actIdx,
                          int* __restrict__ nAct) {
  int b = blockIdx.x;
  int t = threadIdx.x;  // 256
  int lane = t & 63, wv = t >> 6;
  __shared__ int wsum[4];
  __shared__ int sbase;
  if (t == 0) sbase = 0;
  __syncthreads();
  for (int chunk = 0; chunk < 16; ++chunk) {
    int l = chunk * 256 + t;
    int flag = (mmb[(b << 12) + l] == 1.0f) ? 1 : 0;
    unsigned long long m = __ballot(flag);
    int wpre = __popcll(m & ((1ull << lane) - 1ull));
    if (lane == 0) wsum[wv] = __popcll(m);
    __syncthreads();
    int off = sbase;
    for (int w2 = 0; w2 < wv; ++w2) off += wsum[w2];
    if (flag) {
      int pos = off + wpre;
      if (pos < 1024) actIdx[(b << 10) + pos] = l;
    }
    __syncthreads();
    if (t == 0) sbase += wsum[0] + wsum[1] + wsum[2] + wsum[3];
    __syncthreads();
  }
  int total = sbase;
  for (int slot = t; slot < 1024; slot += 256)
    if (slot >= total) actIdx[(b << 10) + slot] = 0;  // safe index; weight will be 0
  if (t == 0) nAct[b] = (total > 1024) ? 1024 : total;
}

// ---------------- K1p: P[b][l][kk*64+c] = f patches (SAME, stride1) ----------------
__global__ void k_build_p(const _Float16* __restrict__ f_h, _Float16* __restrict__ P) {
  int blk = blockIdx.x;  // b*4096+l
  int b = blk >> 12, l = blk & 4095;
  int li = l >> 6, lj = l & 63, c = threadIdx.x;
  _Float16* dst = P + (size_t)blk * 576 + c;
#pragma unroll
  for (int kk = 0; kk < 9; ++kk) {
    int kh = kk / 3, kw = kk % 3;
    int ii = li + kh - 1, jj = lj + kw - 1;
    _Float16 v = (_Float16)0.f;
    if ((unsigned)ii < 64u && (unsigned)jj < 64u)
      v = f_h[((size_t)(b << 12) + ii * 64 + jj) * 64 + c];
    dst[kk * 64] = v;
  }
}

// ---------------- K1c: Rt[b][n][l] = raw x patches (stride2), pre-transposed ----------
__global__ void k_build_rt(const float* __restrict__ x, _Float16* __restrict__ Rt) {
  int kh = blockIdx.x, li = blockIdx.y, b = blockIdx.z;
  int r = 2 * li + kh;
  if (r >= 128) return;  // those Rt entries stay zero (memset)
  __shared__ float xrow[128 * 65];
  for (int t = threadIdx.x; t < 8192; t += 256) {
    int v = t >> 6, c = t & 63;
    xrow[v * 65 + c] = x[((size_t)(b * 128 + r) * 128 + v) * 64 + c];
  }
  __syncthreads();
  for (int idx = threadIdx.x; idx < 12288; idx += 256) {
    int lj = idx & 63, rest = idx >> 6;
    int c = rest & 63, kw = rest >> 6;
    int v = 2 * lj + kw;
    float val = (v < 128) ? xrow[v * 65 + c] : 0.f;
    int n = (kh * 3 + kw) * 64 + c;
    Rt[((size_t)b * 640 + n) * 4096 + li * 64 + lj] = (_Float16)val;
  }
}

// ---------------- K1e: Rts[b][n][s] = Rt[b][n][actIdx[s]] (compacted columns) ---------
__global__ void k_rtsub(const _Float16* __restrict__ Rt, const int* __restrict__ actIdx,
                        _Float16* __restrict__ Rts) {
  int n = blockIdx.x, b = blockIdx.y;
  const _Float16* src = Rt + ((size_t)b * 640 + n) * 4096;
  _Float16* dst = Rts + ((size_t)b * 640 + n) * 1024;
  const int* aIdx = actIdx + (b << 10);
  for (int s = threadIdx.x; s < 1024; s += 256) dst[s] = src[aIdx[s]];
}

// ---------------- K2: symmetric GEMM. S = P*P^T; att[p,l]=S[p,l]*invn[l].
// Only tiles bi<=bj computed; mirror written transposed (scaled by invn[row]). ----------
__global__ __launch_bounds__(256) void k_gemm_sim(const _Float16* __restrict__ P,
                                                  const float* __restrict__ invn,
                                                  float* __restrict__ att) {
  int b = blockIdx.z;
  const _Float16* Ab = P + (size_t)b * 4096 * 576;
  // triangular decode: idx -> (bi <= bj)
  int idx = blockIdx.x;
  int bj = (int)((sqrtf(8.f * (float)idx + 1.f) - 1.f) * 0.5f);
  while ((bj + 1) * (bj + 2) / 2 <= idx) ++bj;
  while (bj * (bj + 1) / 2 > idx) --bj;
  int bi = idx - bj * (bj + 1) / 2;
  int rowBase = bi * 128, colBase = bj * 128;
  bool diag = (bi == bj);

  __shared__ alignas(16) _Float16 As[128 * 32];
  __shared__ alignas(16) _Float16 Bs[128 * 32];
  __shared__ alignas(16) float tbuf[32][132];   // transpose staging (pad 132: 16B-aligned rows)
  int tid = threadIdx.x, wave = tid >> 6, lane = tid & 63;
  int q = lane >> 4, rr = lane & 15;
  int wr = (wave >> 1) * 64, wc = (wave & 1) * 64;
  f32x4 acc[4][4] = {};
  for (int kt = 0; kt < 576; kt += 32) {
    __syncthreads();
#pragma unroll
    for (int t = 0; t < 2; ++t) {
      int chunk = t * 256 + wave * 64 + lane;  // 512 chunks of 16B per tile
      int row = chunk >> 2, kc = (chunk & 3) * 8;
      gload_lds16(Ab + (size_t)(rowBase + row) * 576 + kt + kc,
                  As + (size_t)(t * 256 + wave * 64) * 8);
      if (!diag)
        gload_lds16(Ab + (size_t)(colBase + row) * 576 + kt + kc,
                    Bs + (size_t)(t * 256 + wave * 64) * 8);
    }
    __syncthreads();
    const _Float16* Bsrc = diag ? As : Bs;
    f16x8 af[4], bf[4];
#pragma unroll
    for (int mi = 0; mi < 4; ++mi)
      af[mi] = *(const f16x8*)(As + (wr + mi * 16 + rr) * 32 + q * 8);
#pragma unroll
    for (int ni = 0; ni < 4; ++ni)
      bf[ni] = *(const f16x8*)(Bsrc + (wc + ni * 16 + rr) * 32 + q * 8);
#pragma unroll
    for (int mi = 0; mi < 4; ++mi)
#pragma unroll
      for (int ni = 0; ni < 4; ++ni)
        acc[mi][ni] = __builtin_amdgcn_mfma_f32_16x16x32_f16(af[mi], bf[ni], acc[mi][ni], 0, 0, 0);
  }
  float* attb = att + ((size_t)b << 24);
  // direct tile: rows = p (rowBase), cols = l (colBase), scale invn[col]
#pragma unroll
  for (int ni = 0; ni < 4; ++ni) {
    int gc = colBase + wc + ni * 16 + rr;
    float sc = invn[(b << 12) + gc];
#pragma unroll
    for (int mi = 0; mi < 4; ++mi)
#pragma unroll
      for (int reg = 0; reg < 4; ++reg) {
        int gr = rowBase + wr + mi * 16 + q * 4 + reg;
        attb[((size_t)gr << 12) + gc] = acc[mi][ni][reg] * sc;
      }
  }
  if (diag) return;
  // mirror tile via LDS transpose: att[colBase+c][rowBase+r] = acc[r][c]*invn[rowBase+r]
  const float* ivrow = invn + (b << 12) + rowBase;
#pragma unroll
  for (int ph = 0; ph < 4; ++ph) {
    __syncthreads();
    if ((ph >> 1) == (wc >> 6)) {        // wc=0 -> bands 0,1 ; wc=64 -> bands 2,3
      int nlo = (ph & 1) * 2;
#pragma unroll
      for (int nn = 0; nn < 2; ++nn) {
        int ni = nlo + nn;
        int rloc = nn * 16 + rr;          // row within 32-row band = tile col - ph*32
#pragma unroll
        for (int mi = 0; mi < 4; ++mi)
          *(f32x4*)&tbuf[rloc][wr + mi * 16 + q * 4] = acc[mi][ni];
      }
    }
    __syncthreads();
    int r = tid >> 3;                     // 0..31
    int cbase = (tid & 7) * 16;           // 16 cols per thread
    int grow = colBase + ph * 32 + r;
    float* dst = attb + ((size_t)grow << 12) + rowBase + cbase;
#pragma unroll
    for (int cc = 0; cc < 16; cc += 4) {
      f32x4 v = *(f32x4*)&tbuf[r][cbase + cc];
      f32x4 s = *(const f32x4*)(ivrow + cbase + cc);
      *(f32x4*)(dst + cc) = v * s;
    }
  }
}

// ---------------- K3: fuse (9-pt diagonal stencil) + masked softmax, active cols only --
__global__ __launch_bounds__(256) void k_fuse_softmax2(const float* __restrict__ att,
                                                       const int* __restrict__ actIdx,
                                                       const int* __restrict__ nAct,
                                                       _Float16* __restrict__ Asub) {
  int blk = blockIdx.x;          // b*4096 + p
  int b = blk >> 12, p = blk & 4095;
  const float* Y = att + ((size_t)b << 24);
  const int* aIdx = actIdx + (b << 10);
  int na = nAct[b];
  int tid = threadIdx.x;
  int pi = p >> 6, pj = p & 63;
  int acol = pj * 64 + pi;       // col-major flat index of p
  float z[4];
  float mx = (na < 4096) ? 0.f : -1e30f;  // masked columns contribute logit 0
#pragma unroll
  for (int s4 = 0; s4 < 4; ++s4) {
    int slot = s4 * 256 + tid;
    float zz = -1e30f;
    if (slot < na) {
      int l = aIdx[slot];
      int li = l >> 6, lj = l & 63;
      int bcol = lj * 64 + li;
      float F = 0.f;
#pragma unroll
      for (int d2 = -1; d2 <= 1; ++d2) {
        int a2 = acol + d2, b2 = bcol + d2;
        if ((unsigned)a2 < 4096u && (unsigned)b2 < 4096u) {
          int p2 = (a2 & 63) * 64 + (a2 >> 6);
          int l2 = (b2 & 63) * 64 + (b2 >> 6);
#pragma unroll
          for (int d1 = -1; d1 <= 1; ++d1) {
            int qq = p2 + d1, rr2 = l2 + d1;
            if ((unsigned)qq < 4096u && (unsigned)rr2 < 4096u)
              F += Y[((size_t)qq << 12) + rr2];
          }
        }
      }
      zz = F * 10.f;
    }
    z[s4] = zz;
    mx = fmaxf(mx, zz);
  }
  __shared__ float red[4];
  for (int off = 32; off; off >>= 1) mx = fmaxf(mx, __shfl_down(mx, off));
  if ((tid & 63) == 0) red[tid >> 6] = mx;
  __syncthreads();
  mx = fmaxf(fmaxf(red[0], red[1]), fmaxf(red[2], red[3]));
  float e[4];
  float esum = 0.f;
#pragma unroll
  for (int s4 = 0; s4 < 4; ++s4) {
    int slot = s4 * 256 + tid;
    e[s4] = (slot < na) ? __expf(z[s4] - mx) : 0.f;
    esum += e[s4];
  }
  for (int off = 32; off; off >>= 1) esum += __shfl_down(esum, off);
  __syncthreads();
  if ((tid & 63) == 0) red[tid >> 6] = esum;
  __syncthreads();
  float total = red[0] + red[1] + red[2] + red[3] + (float)(4096 - na) * __expf(0.f - mx);
  float inv = 1.f / total;
  _Float16* Ap = Asub + ((size_t)blk << 10);
#pragma unroll
  for (int s4 = 0; s4 < 4; ++s4) Ap[s4 * 256 + tid] = (_Float16)(e[s4] * inv);
}

// ---------------- K4: G = Asub * Rts^T (K=1024), atomic scatter into y ----------------
__global__ __launch_bounds__(256) void k_gemm_recon(const _Float16* __restrict__ Asub,
                                                    const _Float16* __restrict__ Rts,
                                                    float* __restrict__ y) {
  int b = blockIdx.z;
  const _Float16* Ab = Asub + ((size_t)b << 22);
  const _Float16* Bb = Rts + (size_t)b * 640 * 1024;
  int rowBase = blockIdx.y * 128, colBase = blockIdx.x * 128;  // col over 640
  __shared__ alignas(16) _Float16 As[128 * 32];
  __shared__ alignas(16) _Float16 Bs[128 * 32];
  int tid = threadIdx.x, wave = tid >> 6, lane = tid & 63;
  int q = lane >> 4, rr = lane & 15;
  int wr = (wave >> 1) * 64, wc = (wave & 1) * 64;
  f32x4 acc[4][4] = {};
  for (int kt = 0; kt < 1024; kt += 32) {
    __syncthreads();
#pragma unroll
    for (int t = 0; t < 2; ++t) {
      int chunk = t * 256 + wave * 64 + lane;
      int row = chunk >> 2, kc = (chunk & 3) * 8;
      gload_lds16(Ab + ((size_t)(rowBase + row) << 10) + kt + kc,
                  As + (size_t)(t * 256 + wave * 64) * 8);
      gload_lds16(Bb + ((size_t)(colBase + row) << 10) + kt + kc,
                  Bs + (size_t)(t * 256 + wave * 64) * 8);
    }
    __syncthreads();
    f16x8 af[4], bf[4];
#pragma unroll
    for (int mi = 0; mi < 4; ++mi)
      af[mi] = *(const f16x8*)(As + (wr + mi * 16 + rr) * 32 + q * 8);
#pragma unroll
    for (int ni = 0; ni < 4; ++ni)
      bf[ni] = *(const f16x8*)(Bs + (wc + ni * 16 + rr) * 32 + q * 8);
#pragma unroll
    for (int mi = 0; mi < 4; ++mi)
#pragma unroll
      for (int ni = 0; ni < 4; ++ni)
        acc[mi][ni] = __builtin_amdgcn_mfma_f32_16x16x32_f16(af[mi], bf[ni], acc[mi][ni], 0, 0, 0);
  }
#pragma unroll
  for (int ni = 0; ni < 4; ++ni) {
    int gc = colBase + wc + ni * 16 + rr;
    if (gc < 576) {
      int kk = gc >> 6, c = gc & 63;
      int kh = kk / 3, kw = kk - kh * 3;
#pragma unroll
      for (int mi = 0; mi < 4; ++mi)
#pragma unroll
        for (int reg = 0; reg < 4; ++reg) {
          int gp = rowBase + wr + mi * 16 + q * 4 + reg;
          int i = gp >> 6, j = gp & 63;
          int u = 2 * i + kh, v = 2 * j + kw;
          if (u < 128 && v < 128)
            atomicAdd(y + (((size_t)((b * 128 + u) * 128 + v)) << 6) + c,
                      0.25f * acc[mi][ni][reg]);
        }
    }
  }
}

extern "C" void kernel_launch(void* const* d_in, const int* in_sizes, int n_in,
                              void* d_out, int out_size, void* d_ws, size_t ws_size,
                              hipStream_t stream) {
  const float* x = (const float*)d_in[0];
  const float* mask = (const float*)d_in[1];
  float* out = (float*)d_out;
  float* y = out;                 // [2][128][128][64]
  float* att = out + 2097152;     // [2][4096][4096]

  char* ws = (char*)d_ws;
  _Float16* f_h = (_Float16*)(ws + 0);            //  1,048,576 B
  float* sumsq = (float*)(ws + 0x100000);         //     32,768
  float* mlow = (float*)(ws + 0x108000);          //     32,768
  float* invn = (float*)(ws + 0x110000);          //     32,768
  float* mmb = (float*)(ws + 0x118000);           //     32,768
  _Float16* P = (_Float16*)(ws + 0x120000);       //  9,437,184
  _Float16* Rt = (_Float16*)(ws + 0xA20000);      // 10,485,760  [2][640][4096]
  int* actIdx = (int*)(ws + 0x1420000);           //      8,192  [2][1024]
  int* nAct = (int*)(ws + 0x1422000);             //          8
  _Float16* Rts = (_Float16*)(ws + 0x1430000);    //  2,621,440  [2][640][1024]
  _Float16* Asub = (_Float16*)(ws + 0x16B0000);   // 16,777,216  [2][4096][1024]
  (void)in_sizes; (void)n_in; (void)out_size; (void)ws_size;

  hipMemsetAsync(y, 0, (size_t)2097152 * 4, stream);               // y accumulated via atomics
  hipMemsetAsync(Rt, 0, (size_t)2 * 640 * 4096 * 2, stream);       // pad rows / pad cols zero

  k_pre<<<8192, 64, 0, stream>>>(x, mask, f_h, sumsq, mlow);
  k_norm_mm<<<32, 256, 0, stream>>>(sumsq, mlow, invn, mmb);
  k_compact<<<2, 256, 0, stream>>>(mmb, actIdx, nAct);
  k_build_p<<<8192, 64, 0, stream>>>(f_h, P);
  k_build_rt<<<dim3(3, 64, 2), 256, 0, stream>>>(x, Rt);
  k_rtsub<<<dim3(640, 2), 256, 0, stream>>>(Rt, actIdx, Rts);
  k_gemm_sim<<<dim3(528, 1, 2), 256, 0, stream>>>(P, invn, att);
  k_fuse_softmax2<<<8192, 256, 0, stream>>>(att, actIdx, nAct, Asub);
  k_gemm_recon<<<dim3(5, 32, 2), 256, 0, stream>>>(Asub, Rts, y);
}